// Round 8
// baseline (1489.824 us; speedup 1.0000x reference)
//
#include <hip/hip_runtime.h>
#include <hip/hip_fp16.h>

#define K_NB 81
#define OUTC 8
#define BLK 256
#define KT 16    // k-tile; 81 = 1 + 5*16; 16-lane index runs = full 64B lines
#define NTL 5
#define PITCH 17 // LDS pitch: 2-way bank alias = free (m136)

typedef float v2f __attribute__((ext_vector_type(2)));
typedef float v4f __attribute__((ext_vector_type(4)));

// W2[k][c][l] = dw[k][c] * weight[c][k][l], flat as w2[k*32 + c*8 + l]
__global__ void prep_w2(const float* __restrict__ dw,
                        const float* __restrict__ wt,
                        float* __restrict__ w2) {
    int i = blockIdx.x * blockDim.x + threadIdx.x;
    if (i < K_NB * 32) {
        int k = i >> 5;
        int c = (i >> 3) & 3;
        int l = i & 7;
        w2[i] = dw[k * 4 + c] * wt[(c * K_NB + k) * OUTC + l];
    }
}

union F2H { float f; __half2 h; };

// points [N,3] fp32 -> ph[N] = {half x, half y, half z, half 0} (8B, aligned)
__global__ void repack_points(const float* __restrict__ pts,
                              v2f* __restrict__ ph, int N) {
    int n = blockIdx.x * blockDim.x + threadIdx.x;
    if (n >= N) return;
    float x = pts[3 * n + 0], y = pts[3 * n + 1], z = pts[3 * n + 2];
    F2H a, b;
    a.h = __floats2half2_rn(x, y);
    b.h = __floats2half2_rn(z, 0.f);
    v2f v; v.x = a.f; v.y = b.f;
    ph[n] = v;
}

// (256,4): 4 blocks/CU = 16 waves (R7's (256,3)=12 waves cost 14%), VGPR cap
// 128 >= ~115 live (ireg16 + r_cur32 + r_nxt32 + acc8 + addr).  R6 lesson:
// unbounded alloc -> 256 VGPR + scratch spills; R7 lesson: 3 blocks too few.
__global__ __launch_bounds__(BLK, 4) void conv_main_h(
    const float* __restrict__ points,   // fp32, coalesced self-load
    const v2f*   __restrict__ ph,       // half4-packed points (4 MB, L2-resident)
    const int*   __restrict__ indices,
    const float* __restrict__ w2,
    const float* __restrict__ bias,
    float*       __restrict__ out,
    int N) {
    __shared__ int sidx[BLK * PITCH];   // single buffer; barriers fence reuse

    const int tid = threadIdx.x;
    const int n0  = blockIdx.x * BLK;
    const int n   = n0 + tid;
    const bool valid = n < N;
    const int nc = valid ? n : (N - 1);

    // staging: element e = i*256+tid -> row = i*16 + (tid>>4), col = tid&15
    // (16-lane 64B-contiguous runs: each index line fetched exactly once --
    //  R7's KT=8/32B runs + nt double-fetched every line, +100 MB HBM)
    const int srow = tid >> 4;
    const int scol = tid & 15;

    // stream-once reads: nt to keep L2 ways for ph (R4 lesson: never nt ph)
    const float px = __builtin_nontemporal_load(&points[nc * 3 + 0]);
    const float py = __builtin_nontemporal_load(&points[nc * 3 + 1]);
    const float pz = __builtin_nontemporal_load(&points[nc * 3 + 2]);

    float acc[OUTC];
#pragma unroll
    for (int l = 0; l < OUTC; ++l) {
        float a = bias[l] + w2[24 + l];           // k=0: dist feature = 1.0
        a = fmaf(px, w2[0 + l], a);
        a = fmaf(py, w2[8 + l], a);
        a = fmaf(pz, w2[16 + l], a);
        acc[l] = a;
    }

    auto idx_ld = [&](int t, int i) -> int {
        int gr = n0 + i * 16 + srow;
        if (gr >= N) gr = N - 1;
        return __builtin_nontemporal_load(
            &indices[gr * K_NB + 1 + t * KT + scol]);
    };

    int ireg[KT];
    v2f r_cur[KT];

    // ---- prologue: tile0 ids -> LDS; prefetch tile1 ids; gathers(0) ----
#pragma unroll
    for (int i = 0; i < KT; ++i) ireg[i] = idx_ld(0, i);
#pragma unroll
    for (int i = 0; i < KT; ++i)
        sidx[(i * 16 + srow) * PITCH + scol] = ireg[i];
#pragma unroll
    for (int i = 0; i < KT; ++i) ireg[i] = idx_ld(1, i);
    __syncthreads();
#pragma unroll
    for (int j = 0; j < KT; ++j)
        r_cur[j] = ph[sidx[tid * PITCH + j]];

    // ---- steady state: consume(t) while gathers(t+1) + idx(t+2) in flight.
    // vmcnt FIFO at each wait point stays granular:
    //   ds_write(t+1) waits ireg(t+1) -> vmcnt(16), gathers(t) stay in flight;
    //   consume(t) waits the OLDEST 16 (gathers t) -> newer 32 stay in flight.
#pragma unroll
    for (int t = 0; t < NTL; ++t) {
        v2f r_nxt[KT];
        if (t < NTL - 1) {
            __syncthreads();                       // tile-t LDS reads done
#pragma unroll
            for (int i = 0; i < KT; ++i)
                sidx[(i * 16 + srow) * PITCH + scol] = ireg[i];
            if (t < NTL - 2) {
#pragma unroll
                for (int i = 0; i < KT; ++i) ireg[i] = idx_ld(t + 2, i);
            }
            __syncthreads();
#pragma unroll
            for (int j = 0; j < KT; ++j)
                r_nxt[j] = ph[sidx[tid * PITCH + j]];
        }

        // consume tile t (its gathers were issued one full iteration ago)
#pragma unroll
        for (int j = 0; j < KT; ++j) {
            const int k = 1 + t * KT + j;
            F2H u0, u1; u0.f = r_cur[j].x; u1.f = r_cur[j].y;
            const float2 fxy = __half22float2(u0.h);
            const float  qx = fxy.x, qy = fxy.y;
            const float  qz = __half2float(__low2half(u1.h));
            const float dx = qx - px, dy = qy - py, dz = qz - pz;
            const float dist = fmaf(dx, dx, fmaf(dy, dy, fmaf(dz, dz, 1.0f)));
            const float* __restrict__ w = w2 + k * 32;   // uniform -> s_load
#pragma unroll
            for (int l = 0; l < OUTC; ++l) {
                acc[l] = fmaf(qx, w[l],
                         fmaf(qy, w[8 + l],
                         fmaf(qz, w[16 + l],
                         fmaf(dist, w[24 + l], acc[l]))));
            }
        }

        if (t < NTL - 1) {
#pragma unroll
            for (int j = 0; j < KT; ++j) r_cur[j] = r_nxt[j];   // rename only
        }
    }

    if (valid) {
        v4f lo, hi;
        lo.x = acc[0]; lo.y = acc[1]; lo.z = acc[2]; lo.w = acc[3];
        hi.x = acc[4]; hi.y = acc[5]; hi.z = acc[6]; hi.w = acc[7];
        v4f* o = (v4f*)(out + (long)n * OUTC);
        __builtin_nontemporal_store(lo, o + 0);   // stream-once: keep out of L2
        __builtin_nontemporal_store(hi, o + 1);
    }
}

// ---------- fp32 fallback if ws too small (R5 structure) ----------
__global__ __launch_bounds__(BLK) void conv_main_f32(
    const float* __restrict__ points,
    const int*   __restrict__ indices,
    const float* __restrict__ w2,
    const float* __restrict__ bias,
    float*       __restrict__ out,
    int N) {
    __shared__ int sidx[BLK * 17];
    const int tid = threadIdx.x;
    const int n0  = blockIdx.x * BLK;
    const int n   = n0 + tid;
    const bool valid = n < N;
    const int nc = valid ? n : (N - 1);

    const float px = points[nc * 3 + 0];
    const float py = points[nc * 3 + 1];
    const float pz = points[nc * 3 + 2];
    float acc[OUTC];
#pragma unroll
    for (int l = 0; l < OUTC; ++l) {
        float a = bias[l] + w2[24 + l];
        a = fmaf(px, w2[0 + l], a);
        a = fmaf(py, w2[8 + l], a);
        a = fmaf(pz, w2[16 + l], a);
        acc[l] = a;
    }
    for (int t = 0; t < 5; ++t) {
        __syncthreads();
#pragma unroll
        for (int i = 0; i < 16; ++i) {
            int e = i * BLK + tid;
            int row = e >> 4, col = e & 15;
            int gr = n0 + row;
            if (gr >= N) gr = N - 1;
            sidx[row * 17 + col] = indices[gr * K_NB + 1 + t * 16 + col];
        }
        __syncthreads();
#pragma unroll
        for (int j = 0; j < 16; ++j) {
            const int k  = 1 + t * 16 + j;
            const int id = sidx[tid * 17 + j];
            const float qx = points[id * 3 + 0];
            const float qy = points[id * 3 + 1];
            const float qz = points[id * 3 + 2];
            const float dx = qx - px, dy = qy - py, dz = qz - pz;
            const float dist = fmaf(dx, dx, fmaf(dy, dy, fmaf(dz, dz, 1.0f)));
            const float* __restrict__ w = w2 + k * 32;
#pragma unroll
            for (int l = 0; l < OUTC; ++l) {
                acc[l] = fmaf(qx, w[l],
                         fmaf(qy, w[8 + l],
                         fmaf(qz, w[16 + l],
                         fmaf(dist, w[24 + l], acc[l]))));
            }
        }
    }
    if (valid) {
        float4* o = (float4*)(out + (long)n * OUTC);
        o[0] = make_float4(acc[0], acc[1], acc[2], acc[3]);
        o[1] = make_float4(acc[4], acc[5], acc[6], acc[7]);
    }
}

extern "C" void kernel_launch(void* const* d_in, const int* in_sizes, int n_in,
                              void* d_out, int out_size, void* d_ws, size_t ws_size,
                              hipStream_t stream) {
    const float* points  = (const float*)d_in[0];
    const int*   indices = (const int*)  d_in[1];
    const float* dw      = (const float*)d_in[2];
    const float* wt      = (const float*)d_in[3];
    const float* bias    = (const float*)d_in[4];
    float*       out     = (float*)d_out;

    const int N = in_sizes[0] / 3;

    const size_t ph_bytes = (size_t)N * 8;
    const size_t need     = ph_bytes + K_NB * 32 * sizeof(float);

    if (ws_size >= need) {
        v2f*   ph = (v2f*)d_ws;
        float* w2 = (float*)((char*)d_ws + ph_bytes);
        hipLaunchKernelGGL(prep_w2, dim3((K_NB * 32 + BLK - 1) / BLK), dim3(BLK),
                           0, stream, dw, wt, w2);
        hipLaunchKernelGGL(repack_points, dim3((N + BLK - 1) / BLK), dim3(BLK),
                           0, stream, points, ph, N);
        hipLaunchKernelGGL(conv_main_h, dim3((N + BLK - 1) / BLK), dim3(BLK),
                           0, stream, points, ph, indices, w2, bias, out, N);
    } else {
        float* w2 = (float*)d_ws;
        hipLaunchKernelGGL(prep_w2, dim3((K_NB * 32 + BLK - 1) / BLK), dim3(BLK),
                           0, stream, dw, wt, w2);
        hipLaunchKernelGGL(conv_main_f32, dim3((N + BLK - 1) / BLK), dim3(BLK),
                           0, stream, points, indices, w2, bias, out, N);
    }
}